// Round 2
// baseline (295.140 us; speedup 1.0000x reference)
//
#include <hip/hip_runtime.h>
#include <hip/hip_bf16.h>

// Problem constants: N=32, C=3, H=W=512, A=512, SCALE=1, ITERS=5, thr0=4.0f.
#define AN 512
#define NB 32
#define HW 512

__device__ __forceinline__ float waveMax(float v) {
    #pragma unroll
    for (int off = 32; off > 0; off >>= 1) v = fmaxf(v, __shfl_xor(v, off, 64));
    return v;
}
__device__ __forceinline__ float waveSum(float v) {
    #pragma unroll
    for (int off = 32; off > 0; off >>= 1) v += __shfl_xor(v, off, 64);
    return v;
}

// ---------------------------------------------------------------------------
// Kernel 1: water-fill + inverse-CDF coords. One block per sample.
// Wave shfl reductions (barrier-free within wave) + 8-entry LDS combine;
// Hillis-Steele inclusive scan for the cumsum (9 passes).
// ---------------------------------------------------------------------------
__global__ __launch_bounds__(512) void waterfill_coords_kernel(
    const float* __restrict__ attx, const float* __restrict__ atty,
    float* __restrict__ gx, float* __restrict__ gy)
{
    __shared__ float axs[AN], ays[AN], csx[AN], csy[AN];
    __shared__ float wrx[8], wry[8];
    const int n = blockIdx.x;
    const int t = threadIdx.x;
    const int wid = t >> 6;

    float ax = attx[n * AN + t] * 512.0f;
    float ay = atty[n * AN + t] * 512.0f;

    for (int j = 0; j < 5; ++j) {
        // block max via wave butterfly + LDS combine
        float mx = waveMax(ax), my = waveMax(ay);
        if ((t & 63) == 0) { wrx[wid] = mx; wry[wid] = my; }
        __syncthreads();
        float Mx = wrx[0], My = wry[0];
        #pragma unroll
        for (int i = 1; i < 8; ++i) { Mx = fmaxf(Mx, wrx[i]); My = fmaxf(My, wry[i]); }
        float thr = fminf(Mx, My);
        if (j == 0) thr = fminf(thr, 4.0f);
        ax = fminf(ax, thr);
        ay = fminf(ay, thr);

        // block sum
        float sx = waveSum(ax), sy = waveSum(ay);
        __syncthreads();                       // done reading wrx/wry
        if ((t & 63) == 0) { wrx[wid] = sx; wry[wid] = sy; }
        __syncthreads();
        float Sx = 0.0f, Sy = 0.0f;
        #pragma unroll
        for (int i = 0; i < 8; ++i) { Sx += wrx[i]; Sy += wry[i]; }
        ax += (512.0f - Sx) / 512.0f;
        ay += (512.0f - Sy) / 512.0f;
        __syncthreads();                       // done reading before next-iter write
    }

    if (t == 0) { ax = 1.0f; ay = 1.0f; }      // ax.at[:,0].set(1.0)
    axs[t] = ax; ays[t] = ay; csx[t] = ax; csy[t] = ay;
    __syncthreads();

    // Hillis-Steele inclusive scan (both axes share barriers)
    #pragma unroll
    for (int s = 1; s < AN; s <<= 1) {
        float vx = (t >= s) ? csx[t - s] : 0.0f;
        float vy = (t >= s) ? csy[t - s] : 0.0f;
        __syncthreads();
        csx[t] += vx; csy[t] += vy;
        __syncthreads();
    }

    // height coords (from ax cumsum) -> gy
    {
        float step = csx[AN - 1] / 512.0f;
        float tv = (float)(t + 1) * step;
        int lo = 0, hi = AN;
        while (lo < hi) { int mid = (lo + hi) >> 1; if (csx[mid] < tv) lo = mid + 1; else hi = mid; }
        int j = lo > (AN - 1) ? (AN - 1) : lo;
        float prev = (j > 0) ? csx[j - 1] : 0.0f;
        float frac = (tv - prev) / fmaxf(axs[j], 1e-12f);
        gy[n * AN + t] = ((float)j + frac) * (2.0f / 512.0f) - 1.0f;
    }
    // width coords (from ay cumsum) -> gx
    {
        float step = csy[AN - 1] / 512.0f;
        float tv = (float)(t + 1) * step;
        int lo = 0, hi = AN;
        while (lo < hi) { int mid = (lo + hi) >> 1; if (csy[mid] < tv) lo = mid + 1; else hi = mid; }
        int j = lo > (AN - 1) ? (AN - 1) : lo;
        float prev = (j > 0) ? csy[j - 1] : 0.0f;
        float frac = (tv - prev) / fmaxf(ays[j], 1e-12f);
        gx[n * AN + t] = ((float)j + frac) * (2.0f / 512.0f) - 1.0f;
    }
}

// ---------------------------------------------------------------------------
// Kernel 2: separable bilinear grid-sample + grid write.
// 4 consecutive wo per thread; 128 threads per output row, 2 rows per block.
// y-side math amortized over 4 px; stores vectorized to dwordx4; validity
// folded into weights (clamped gather addresses are always in-bounds).
// ---------------------------------------------------------------------------
__global__ __launch_bounds__(256) void grid_sample_kernel(
    const float* __restrict__ data, const float* __restrict__ gx,
    const float* __restrict__ gy, float* __restrict__ outS,
    float* __restrict__ outG)
{
    const int lane   = threadIdx.x & 127;     // 128 threads per row
    const int rowsel = threadIdx.x >> 7;      // 0/1
    const int ho = blockIdx.x * 2 + rowsel;
    const int n  = blockIdx.y;
    const int wo = lane * 4;

    const float gyv = gy[n * AN + ho];
    const float4 gx4 = ((const float4*)(gx + n * AN))[lane];

    // y-side (shared across the 4 pixels)
    const float y   = (gyv + 1.0f) * 256.0f - 0.5f;
    const float y0f = floorf(y);
    const float wy1 = y - y0f, wy0 = 1.0f - wy1;
    const float vy0 = ((y0f >= 0.0f) & (y0f < 512.0f)) ? 1.0f : 0.0f;
    const float vy1 = ((y0f >= -1.0f) & (y0f < 511.0f)) ? 1.0f : 0.0f;
    const int y0 = (int)fminf(fmaxf(y0f, 0.0f), 511.0f);
    const int y1 = (int)fminf(fmaxf(y0f + 1.0f, 0.0f), 511.0f);
    const size_t r0 = (size_t)y0 * HW, r1 = (size_t)y1 * HW;

    const float* base = data + (size_t)n * 3 * HW * HW;
    float res[3][4];
    float gv[8];
    const float xg[4] = {gx4.x, gx4.y, gx4.z, gx4.w};

    #pragma unroll
    for (int k = 0; k < 4; ++k) {
        const float gxv = xg[k];
        gv[2 * k] = gxv; gv[2 * k + 1] = gyv;
        const float x   = (gxv + 1.0f) * 256.0f - 0.5f;
        const float x0f = floorf(x);
        const float wx1 = x - x0f, wx0 = 1.0f - wx1;
        const float vx0 = ((x0f >= 0.0f) & (x0f < 512.0f)) ? 1.0f : 0.0f;
        const float vx1 = ((x0f >= -1.0f) & (x0f < 511.0f)) ? 1.0f : 0.0f;
        const int x0 = (int)fminf(fmaxf(x0f, 0.0f), 511.0f);
        const int x1 = (int)fminf(fmaxf(x0f + 1.0f, 0.0f), 511.0f);
        const float w00 = wx0 * wy0 * vx0 * vy0;
        const float w10 = wx1 * wy0 * vx1 * vy0;
        const float w01 = wx0 * wy1 * vx0 * vy1;
        const float w11 = wx1 * wy1 * vx1 * vy1;
        #pragma unroll
        for (int c = 0; c < 3; ++c) {
            const float* p = base + (size_t)c * HW * HW;
            res[c][k] = p[r0 + x0] * w00 + p[r0 + x1] * w10
                      + p[r1 + x0] * w01 + p[r1 + x1] * w11;
        }
    }

    const size_t o = (((size_t)n * 3) * HW + ho) * HW + wo;
    #pragma unroll
    for (int c = 0; c < 3; ++c)
        *(float4*)(outS + o + (size_t)c * HW * HW) =
            make_float4(res[c][0], res[c][1], res[c][2], res[c][3]);

    float4* gptr = (float4*)(outG + (((size_t)n * HW + ho) * HW + wo) * 2);
    gptr[0] = make_float4(gv[0], gv[1], gv[2], gv[3]);
    gptr[1] = make_float4(gv[4], gv[5], gv[6], gv[7]);
}

extern "C" void kernel_launch(void* const* d_in, const int* in_sizes, int n_in,
                              void* d_out, int out_size, void* d_ws, size_t ws_size,
                              hipStream_t stream) {
    const float* data = (const float*)d_in[0];   // (32,3,512,512)
    const float* attx = (const float*)d_in[1];   // (32,512)
    const float* atty = (const float*)d_in[2];   // (32,512)

    float* gx = (float*)d_ws;            // (32,512) width coords
    float* gy = gx + NB * AN;            // (32,512) height coords

    float* outS = (float*)d_out;                          // sampled (32,3,512,512)
    float* outG = outS + (size_t)NB * 3 * HW * HW;        // grid (32,512,512,2)

    waterfill_coords_kernel<<<NB, AN, 0, stream>>>(attx, atty, gx, gy);

    dim3 grid(HW / 2, NB);
    grid_sample_kernel<<<grid, 256, 0, stream>>>(data, gx, gy, outS, outG);
}

// Round 3
// 245.998 us; speedup vs baseline: 1.1998x; 1.1998x over previous
//
#include <hip/hip_runtime.h>
#include <hip/hip_bf16.h>

// Problem constants: N=32, C=3, H=W=512, A=512, SCALE=1, ITERS=5, thr0=4.0f.
#define AN 512
#define NB 32
#define HW 512

__device__ __forceinline__ float waveMax(float v) {
    #pragma unroll
    for (int off = 32; off > 0; off >>= 1) v = fmaxf(v, __shfl_xor(v, off, 64));
    return v;
}
__device__ __forceinline__ float waveSum(float v) {
    #pragma unroll
    for (int off = 32; off > 0; off >>= 1) v += __shfl_xor(v, off, 64);
    return v;
}

// ---------------------------------------------------------------------------
// Kernel 1: water-fill + inverse-CDF coords. One block per sample.
// Wave shfl reductions + 8-entry LDS combine; Hillis-Steele scan for cumsum.
// ---------------------------------------------------------------------------
__global__ __launch_bounds__(512) void waterfill_coords_kernel(
    const float* __restrict__ attx, const float* __restrict__ atty,
    float* __restrict__ gx, float* __restrict__ gy)
{
    __shared__ float axs[AN], ays[AN], csx[AN], csy[AN];
    __shared__ float wrx[8], wry[8];
    const int n = blockIdx.x;
    const int t = threadIdx.x;
    const int wid = t >> 6;

    float ax = attx[n * AN + t] * 512.0f;
    float ay = atty[n * AN + t] * 512.0f;

    for (int j = 0; j < 5; ++j) {
        float mx = waveMax(ax), my = waveMax(ay);
        if ((t & 63) == 0) { wrx[wid] = mx; wry[wid] = my; }
        __syncthreads();
        float Mx = wrx[0], My = wry[0];
        #pragma unroll
        for (int i = 1; i < 8; ++i) { Mx = fmaxf(Mx, wrx[i]); My = fmaxf(My, wry[i]); }
        float thr = fminf(Mx, My);
        if (j == 0) thr = fminf(thr, 4.0f);
        ax = fminf(ax, thr);
        ay = fminf(ay, thr);

        float sx = waveSum(ax), sy = waveSum(ay);
        __syncthreads();
        if ((t & 63) == 0) { wrx[wid] = sx; wry[wid] = sy; }
        __syncthreads();
        float Sx = 0.0f, Sy = 0.0f;
        #pragma unroll
        for (int i = 0; i < 8; ++i) { Sx += wrx[i]; Sy += wry[i]; }
        ax += (512.0f - Sx) / 512.0f;
        ay += (512.0f - Sy) / 512.0f;
        __syncthreads();
    }

    if (t == 0) { ax = 1.0f; ay = 1.0f; }
    axs[t] = ax; ays[t] = ay; csx[t] = ax; csy[t] = ay;
    __syncthreads();

    #pragma unroll
    for (int s = 1; s < AN; s <<= 1) {
        float vx = (t >= s) ? csx[t - s] : 0.0f;
        float vy = (t >= s) ? csy[t - s] : 0.0f;
        __syncthreads();
        csx[t] += vx; csy[t] += vy;
        __syncthreads();
    }

    {
        float step = csx[AN - 1] / 512.0f;
        float tv = (float)(t + 1) * step;
        int lo = 0, hi = AN;
        while (lo < hi) { int mid = (lo + hi) >> 1; if (csx[mid] < tv) lo = mid + 1; else hi = mid; }
        int j = lo > (AN - 1) ? (AN - 1) : lo;
        float prev = (j > 0) ? csx[j - 1] : 0.0f;
        float frac = (tv - prev) / fmaxf(axs[j], 1e-12f);
        gy[n * AN + t] = ((float)j + frac) * (2.0f / 512.0f) - 1.0f;
    }
    {
        float step = csy[AN - 1] / 512.0f;
        float tv = (float)(t + 1) * step;
        int lo = 0, hi = AN;
        while (lo < hi) { int mid = (lo + hi) >> 1; if (csy[mid] < tv) lo = mid + 1; else hi = mid; }
        int j = lo > (AN - 1) ? (AN - 1) : lo;
        float prev = (j > 0) ? csy[j - 1] : 0.0f;
        float frac = (tv - prev) / fmaxf(ays[j], 1e-12f);
        gx[n * AN + t] = ((float)j + frac) * (2.0f / 512.0f) - 1.0f;
    }
}

// ---------------------------------------------------------------------------
// Kernel 2: separable bilinear grid-sample via LDS row staging.
// One block per (ho, n): all 512 output px of a row read only source rows
// y0,y1 (x3 channels) = 12 KB -> staged to LDS with coalesced float4 loads.
// Gathers then hit LDS (stride~2 banks = free). Global access is 100%
// coalesced in both directions -> HBM-roofline bound.
// ---------------------------------------------------------------------------
__global__ __launch_bounds__(256) void grid_sample_kernel(
    const float* __restrict__ data, const float* __restrict__ gx,
    const float* __restrict__ gy, float* __restrict__ outS,
    float* __restrict__ outG)
{
    __shared__ float rows[6][HW];   // [y0: c0,c1,c2 | y1: c0,c1,c2][x]
    const int t  = threadIdx.x;
    const int ho = blockIdx.x;
    const int n  = blockIdx.y;

    const float gyv = gy[n * AN + ho];
    const float y   = (gyv + 1.0f) * 256.0f - 0.5f;
    const float y0f = floorf(y);
    const float wy1 = y - y0f, wy0 = 1.0f - wy1;
    const float vy0 = ((y0f >= 0.0f) & (y0f < 512.0f)) ? 1.0f : 0.0f;
    const float vy1 = ((y0f >= -1.0f) & (y0f < 511.0f)) ? 1.0f : 0.0f;
    const int y0 = (int)fminf(fmaxf(y0f, 0.0f), 511.0f);
    const int y1 = (int)fminf(fmaxf(y0f + 1.0f, 0.0f), 511.0f);

    // stage 6 source rows (2 y x 3 c), 128 float4 each = 768 float4, 3/thread
    const float* base = data + (size_t)n * 3 * HW * HW;
    #pragma unroll
    for (int r = 0; r < 3; ++r) {
        const int idx = r * 256 + t;
        const int row = idx >> 7;        // 0..5
        const int col = idx & 127;       // float4 index within row
        const int yy  = (row < 3) ? y0 : y1;
        const int c   = (row < 3) ? row : row - 3;
        float4 v = ((const float4*)(base + ((size_t)c * HW + yy) * HW))[col];
        ((float4*)&rows[row][0])[col] = v;
    }
    __syncthreads();

    // 2 consecutive px per thread
    const float2 gx2 = ((const float2*)(gx + n * AN))[t];
    const float xg[2] = {gx2.x, gx2.y};
    float res[3][2];

    #pragma unroll
    for (int k = 0; k < 2; ++k) {
        const float gxv = xg[k];
        const float x   = (gxv + 1.0f) * 256.0f - 0.5f;
        const float x0f = floorf(x);
        const float wx1 = x - x0f, wx0 = 1.0f - wx1;
        const float vx0 = ((x0f >= 0.0f) & (x0f < 512.0f)) ? 1.0f : 0.0f;
        const float vx1 = ((x0f >= -1.0f) & (x0f < 511.0f)) ? 1.0f : 0.0f;
        const int x0 = (int)fminf(fmaxf(x0f, 0.0f), 511.0f);
        const int x1 = (int)fminf(fmaxf(x0f + 1.0f, 0.0f), 511.0f);
        const float w00 = wx0 * wy0 * vx0 * vy0;
        const float w10 = wx1 * wy0 * vx1 * vy0;
        const float w01 = wx0 * wy1 * vx0 * vy1;
        const float w11 = wx1 * wy1 * vx1 * vy1;
        #pragma unroll
        for (int c = 0; c < 3; ++c) {
            res[c][k] = rows[c][x0] * w00 + rows[c][x1] * w10
                      + rows[3 + c][x0] * w01 + rows[3 + c][x1] * w11;
        }
    }

    const int wo = 2 * t;
    const size_t o = (((size_t)n * 3) * HW + ho) * HW + wo;
    #pragma unroll
    for (int c = 0; c < 3; ++c)
        *(float2*)(outS + o + (size_t)c * HW * HW) = make_float2(res[c][0], res[c][1]);

    *(float4*)(outG + (((size_t)n * HW + ho) * HW + wo) * 2) =
        make_float4(gx2.x, gyv, gx2.y, gyv);
}

extern "C" void kernel_launch(void* const* d_in, const int* in_sizes, int n_in,
                              void* d_out, int out_size, void* d_ws, size_t ws_size,
                              hipStream_t stream) {
    const float* data = (const float*)d_in[0];   // (32,3,512,512)
    const float* attx = (const float*)d_in[1];   // (32,512)
    const float* atty = (const float*)d_in[2];   // (32,512)

    float* gx = (float*)d_ws;            // (32,512) width coords
    float* gy = gx + NB * AN;            // (32,512) height coords

    float* outS = (float*)d_out;                          // sampled (32,3,512,512)
    float* outG = outS + (size_t)NB * 3 * HW * HW;        // grid (32,512,512,2)

    waterfill_coords_kernel<<<NB, AN, 0, stream>>>(attx, atty, gx, gy);

    dim3 grid(HW, NB);
    grid_sample_kernel<<<grid, 256, 0, stream>>>(data, gx, gy, outS, outG);
}